// Round 10
// baseline (575.247 us; speedup 1.0000x reference)
//
#include <hip/hip_runtime.h>
#include <stdint.h>

#define B_SZ 128
#define T_SZ 800
#define I_SZ 300
#define KPAD 320     // W_ih K padded with zeros to 320
#define H_SZ 32
#define G_SZ 128
#define NWIN 50      // 800 / 16
#define NBUF 4       // gx window buffers
#define TP   808     // hist stride (f16 elems): 16B-aligned rows
#define NTILE 50     // T_SZ/16 s-tiles
#define NGRP 13      // ceil(NTILE/4) tile-groups per batch

typedef float f32x4 __attribute__((ext_vector_type(4)));
typedef _Float16 half8 __attribute__((ext_vector_type(8)));
typedef _Float16 half2v __attribute__((ext_vector_type(2)));

union FragH { half8 v; _Float16 h[8]; uint4 u4; };
union PkU  { uint u; _Float16 h[2]; };
union HsU  { ushort s; _Float16 h; };
union Pk2  { uint u; half2v v; };

#if __has_builtin(__builtin_amdgcn_permlane32_swap)
#define HAVE_PL32 1
#else
#define HAVE_PL32 0
#endif

#if __has_builtin(__builtin_amdgcn_fdot2) && __has_builtin(__builtin_amdgcn_mov_dpp)
#define HAVE_DOT2 1
#else
#define HAVE_DOT2 0
#endif

__device__ __forceinline__ float tanhfast(float x) {
    float ax = fabsf(x);
    float z = __expf(-2.f * ax);
    float r = __fdividef(1.f - z, 1.f + z);
    return __builtin_copysignf(r, x);
}
__device__ __forceinline__ float sigmoidf_(float x) {
    return __fdividef(1.f, 1.f + __expf(-x));
}
__device__ __forceinline__ float bcast_lane(float v, int srclane) {
    return __int_as_float(__builtin_amdgcn_readlane(__float_as_int(v), srclane));
}

// ============ k_prep: W_ih f32 -> f16 (K zero-padded to 320); Ww f32 -> f16 ============
__global__ __launch_bounds__(256) void k_prep(
    const float* __restrict__ W_ih, const float* __restrict__ Ww,
    _Float16* __restrict__ W_ihH, _Float16* __restrict__ WwH)
{
    int i = blockIdx.x * 256 + threadIdx.x;
    if (i < G_SZ * KPAD) {
        int r = i / KPAD, k = i - r * KPAD;
        W_ihH[i] = (k < I_SZ) ? (_Float16)W_ih[r * I_SZ + k] : (_Float16)0.f;
    }
    int j = i - G_SZ * KPAD;
    if (j >= 0 && j < T_SZ * T_SZ) WwH[j] = (_Float16)Ww[j];
}

// ============ k_main: dual-batch scan + producers ============
// R10: the scan wave is ~78% stall (dep-latency bubbles: readlane->fdot2 chain, 6
// transcendentals; VALUBusy arithmetic from R9). Fill the bubbles with a SECOND
// independent recurrence: each block handles batches 2b, 2b+1; the scan wave runs both
// interleaved (per-batch op order unchanged -> bit-identical numerics). Grid 64 blocks.
// LDS: histA+histB (103 KB) + gxbuf[2] (32 KB) = 136 KB (< 160 KB gfx950 workgroup max).
// Producers compute both batches' windows (they were ~90% idle at 1 batch).
__global__ __launch_bounds__(256) void k_main(
    const float* __restrict__ x, const _Float16* __restrict__ W_ihH,
    const float* __restrict__ W_hh,
    const float* __restrict__ b_ih, const float* __restrict__ b_hh,
    const float* __restrict__ bfc,
    _Float16* __restrict__ histG,
    float* __restrict__ out)
{
    const int bA   = blockIdx.x * 2;
    const int bB   = bA + 1;
    const int tid  = threadIdx.x;
    const int wave = tid >> 6;
    const int lane = tid & 63;
    const int m16  = lane & 15;
    const int quad = lane >> 4;

    __shared__ __align__(16) ushort histA[H_SZ][TP];        // 51712 B
    __shared__ __align__(16) ushort histB[H_SZ][TP];        // 51712 B
    __shared__ __align__(16) uint   gxbuf[2][NBUF][16][64]; // 32768 B
    __shared__ int produced, consumed;

    if (tid == 0) { produced = 0; consumed = 0; out[bA] = bfc[0]; out[bB] = bfc[0]; }
    __syncthreads();

    if (wave == 0) {
        // ---------------- consumer: dual LSTM scan (interleaved, independent) ----------------
#if HAVE_PL32
        bool pl_pick_x;
        {
            auto t2 = __builtin_amdgcn_permlane32_swap(lane, lane, false, false);
            pl_pick_x = ((int)__builtin_amdgcn_readlane((int)t2[0], 63) < (int)H_SZ);
        }
#endif
        float cA = 0.f, cB = 0.f;

#if HAVE_DOT2 && HAVE_PL32
        // W_hh rows lane / lane+64 as packed f16 pairs (shared by both batches)
        uint WpA[16], WpB[16];
#pragma unroll
        for (int j = 0; j < 16; ++j) {
            HsU a0_, a1_, b0_, b1_;
            a0_.h = (_Float16)W_hh[lane * H_SZ + 2*j];
            a1_.h = (_Float16)W_hh[lane * H_SZ + 2*j + 1];
            b0_.h = (_Float16)W_hh[(lane + 64) * H_SZ + 2*j];
            b1_.h = (_Float16)W_hh[(lane + 64) * H_SZ + 2*j + 1];
            WpA[j] = (uint)a0_.s | ((uint)a1_.s << 16);
            WpB[j] = (uint)b0_.s | ((uint)b1_.s << 16);
        }
        int hpkA = 0, hpkB = 0;   // even lane 32+2j: packed {h[2j],h[2j+1]} f16; h(-1)=0

        for (int w = 0; w < NWIN; ++w) {
            while (__atomic_load_n(&produced, __ATOMIC_ACQUIRE) < w + 1)
                __builtin_amdgcn_s_sleep(2);
            const int wb = w & (NBUF - 1);
#pragma unroll 4
            for (int tl = 0; tl < 16; ++tl) {
                const int t = w * 16 + tl;
                PkU gA; gA.u = gxbuf[0][wb][tl][lane];
                PkU gB; gB.u = gxbuf[1][wb][tl][lane];
                float fA0=0.f,fA1=0.f,oA0=0.f,oA1=0.f;   // batch A gate accums
                float fB0=0.f,fB1=0.f,oB0=0.f,oB1=0.f;   // batch B gate accums
#pragma unroll
                for (int j = 0; j < 16; j += 2) {
                    Pk2 hA0; hA0.u = (uint)__builtin_amdgcn_readlane(hpkA, 32 + 2*j);
                    Pk2 hB0; hB0.u = (uint)__builtin_amdgcn_readlane(hpkB, 32 + 2*j);
                    Pk2 hA1; hA1.u = (uint)__builtin_amdgcn_readlane(hpkA, 32 + 2*j + 2);
                    Pk2 hB1; hB1.u = (uint)__builtin_amdgcn_readlane(hpkB, 32 + 2*j + 2);
                    Pk2 wa0; wa0.u = WpA[j];     Pk2 wb0; wb0.u = WpB[j];
                    Pk2 wa1; wa1.u = WpA[j + 1]; Pk2 wb1; wb1.u = WpB[j + 1];
                    fA0 = __builtin_amdgcn_fdot2(wa0.v, hA0.v, fA0, false);
                    fB0 = __builtin_amdgcn_fdot2(wa0.v, hB0.v, fB0, false);
                    oA0 = __builtin_amdgcn_fdot2(wb0.v, hA0.v, oA0, false);
                    oB0 = __builtin_amdgcn_fdot2(wb0.v, hB0.v, oB0, false);
                    fA1 = __builtin_amdgcn_fdot2(wa1.v, hA1.v, fA1, false);
                    fB1 = __builtin_amdgcn_fdot2(wa1.v, hB1.v, fB1, false);
                    oA1 = __builtin_amdgcn_fdot2(wb1.v, hA1.v, oA1, false);
                    oB1 = __builtin_amdgcn_fdot2(wb1.v, hB1.v, oB1, false);
                }
                float g0A = (fA0 + fA1) + (float)gA.h[0];
                float g0B = (fB0 + fB1) + (float)gB.h[0];
                float g1A = (oA0 + oA1) + (float)gA.h[1];
                float g1B = (oB0 + oB1) + (float)gB.h[1];

                float a0A = sigmoidf_(g0A);
                float a0B = sigmoidf_(g0B);
                float zzA = (lane < H_SZ) ? g1A : 0.5f * g1A;
                float zzB = (lane < H_SZ) ? g1B : 0.5f * g1B;
                float thA = tanhfast(zzA);
                float thB = tanhfast(zzB);
                float a1A = (lane < H_SZ) ? thA : 0.5f * thA + 0.5f;
                float a1B = (lane < H_SZ) ? thB : 0.5f * thB + 0.5f;

                float igA = a0A * a1A;
                float igB = a0B * a1B;
                auto rrA = __builtin_amdgcn_permlane32_swap(
                    __float_as_int(igA), __float_as_int(igA), false, false);
                auto rrB = __builtin_amdgcn_permlane32_swap(
                    __float_as_int(igB), __float_as_int(igB), false, false);
                float igsA = __int_as_float(pl_pick_x ? (int)rrA[0] : (int)rrA[1]);
                float igsB = __int_as_float(pl_pick_x ? (int)rrB[0] : (int)rrB[1]);
                cA = a0A * cA + igsA;
                cB = a0B * cB + igsB;
                float hA = a1A * tanhfast(cA);
                float hB = a1B * tanhfast(cB);

                HsU hcA; hcA.h = (_Float16)hA;
                HsU hcB; hcB.h = (_Float16)hB;
                uint hcuA = (uint)hcA.s, hcuB = (uint)hcB.s;
                uint hnbA = (uint)__builtin_amdgcn_mov_dpp((int)hcuA, 0xB1, 0xF, 0xF, false);
                uint hnbB = (uint)__builtin_amdgcn_mov_dpp((int)hcuB, 0xB1, 0xF, 0xF, false);
                hpkA = (int)((hnbA << 16) | hcuA);
                hpkB = (int)((hnbB << 16) | hcuB);
                if (lane >= H_SZ) {
                    histA[lane - H_SZ][t] = hcA.s;
                    histB[lane - H_SZ][t] = hcB.s;
                }
            }
            __atomic_store_n(&consumed, w + 1, __ATOMIC_RELEASE);
        }
#else
        // -------- fallback: dual-batch scalar-f32 scan (R2-style, sequential per step) --------
        float W0[H_SZ], W1[H_SZ];
#pragma unroll
        for (int k = 0; k < H_SZ; ++k) W0[k] = W_hh[lane * H_SZ + k];
#pragma unroll
        for (int k = 0; k < H_SZ; ++k) W1[k] = W_hh[(lane + 64) * H_SZ + k];
        float hpA = 0.f, hpB = 0.f;

        for (int w = 0; w < NWIN; ++w) {
            while (__atomic_load_n(&produced, __ATOMIC_ACQUIRE) < w + 1)
                __builtin_amdgcn_s_sleep(2);
            const int wb = w & (NBUF - 1);
#pragma unroll 2
            for (int tl = 0; tl < 16; ++tl) {
                const int t = w * 16 + tl;
                for (int sel = 0; sel < 2; ++sel) {
                    float& c = sel ? cB : cA;
                    float& hp = sel ? hpB : hpA;
                    PkU g; g.u = gxbuf[sel][wb][tl][lane];
                    float p0=0.f,p1=0.f,p2=0.f,p3=0.f;
                    float q0=0.f,q1=0.f,q2=0.f,q3=0.f;
#pragma unroll
                    for (int k = 0; k < H_SZ; k += 4) {
                        float h0 = bcast_lane(hp, H_SZ + k + 0);
                        float h1 = bcast_lane(hp, H_SZ + k + 1);
                        float h2 = bcast_lane(hp, H_SZ + k + 2);
                        float h3 = bcast_lane(hp, H_SZ + k + 3);
                        p0 += W0[k+0]*h0; q0 += W1[k+0]*h0;
                        p1 += W0[k+1]*h1; q1 += W1[k+1]*h1;
                        p2 += W0[k+2]*h2; q2 += W1[k+2]*h2;
                        p3 += W0[k+3]*h3; q3 += W1[k+3]*h3;
                    }
                    float g0 = ((p0 + p1) + (p2 + p3)) + (float)g.h[0];
                    float g1 = ((q0 + q1) + (q2 + q3)) + (float)g.h[1];
                    float a0 = sigmoidf_(g0);
                    float zz = (lane < H_SZ) ? g1 : 0.5f * g1;
                    float th = tanhfast(zz);
                    float a1 = (lane < H_SZ) ? th : 0.5f * th + 0.5f;
                    float ig  = a0 * a1;
                    float igs = __shfl_up(ig, 32, 64);
                    c = a0 * c + igs;
                    float h = a1 * tanhfast(c);
                    hp = h;
                    if (lane >= H_SZ) {
                        HsU hs; hs.h = (_Float16)h;
                        if (sel) histB[lane - H_SZ][t] = hs.s;
                        else     histA[lane - H_SZ][t] = hs.s;
                    }
                }
            }
            __atomic_store_n(&consumed, w + 1, __ATOMIC_RELEASE);
        }
#endif
    } else {
        // ---------------- producers: gx windows via f16 MFMA, both batches ----------------
        float bias[8];
#pragma unroll
        for (int nt = 0; nt < 8; ++nt)
            bias[nt] = b_ih[nt * 16 + m16] + b_hh[nt * 16 + m16];
        const float* xbA = x + (size_t)bA * T_SZ * I_SZ;
        const float* xbB = x + (size_t)bB * T_SZ * I_SZ;

        auto gxcompute = [&](const float* xrow, f32x4 (&acc)[8]) {
#pragma unroll
            for (int nt = 0; nt < 8; ++nt) acc[nt] = (f32x4){0.f, 0.f, 0.f, 0.f};
            for (int ks = 0; ks < 9; ++ks) {           // k = 0..287
                const int k0 = ks * 32 + quad * 8;
                f32x4 x0 = *(const f32x4*)(xrow + k0);
                f32x4 x1 = *(const f32x4*)(xrow + k0 + 4);
                FragH a;
                a.h[0] = (_Float16)x0[0]; a.h[1] = (_Float16)x0[1];
                a.h[2] = (_Float16)x0[2]; a.h[3] = (_Float16)x0[3];
                a.h[4] = (_Float16)x1[0]; a.h[5] = (_Float16)x1[1];
                a.h[6] = (_Float16)x1[2]; a.h[7] = (_Float16)x1[3];
#pragma unroll
                for (int nt = 0; nt < 8; ++nt) {
                    FragH bb;
                    bb.u4 = *(const uint4*)(W_ihH + (size_t)(nt * 16 + m16) * KPAD + k0);
                    acc[nt] = __builtin_amdgcn_mfma_f32_16x16x32_f16(a.v, bb.v, acc[nt], 0, 0, 0);
                }
            }
            {   // tail k = 288..299 (x predicated; W_ihH zero-padded to 320)
                FragH a;
#pragma unroll
                for (int jj = 0; jj < 8; ++jj) {
                    int k = 288 + quad * 8 + jj;
                    a.h[jj] = (k < I_SZ) ? (_Float16)xrow[k] : (_Float16)0.f;
                }
#pragma unroll
                for (int nt = 0; nt < 8; ++nt) {
                    FragH bb;
                    bb.u4 = *(const uint4*)(W_ihH + (size_t)(nt * 16 + m16) * KPAD + 288 + quad * 8);
                    acc[nt] = __builtin_amdgcn_mfma_f32_16x16x32_f16(a.v, bb.v, acc[nt], 0, 0, 0);
                }
            }
        };
        auto gxstore = [&](int sel, int wb, f32x4 (&acc)[8]) {
            // C/D: row(tl) = quad*4+r, col = nt*16+m16. Pack (col, col+64) f16 pair.
#pragma unroll
            for (int nt = 0; nt < 4; ++nt)
#pragma unroll
                for (int r = 0; r < 4; ++r) {
                    PkU p;
                    p.h[0] = (_Float16)(acc[nt][r]     + bias[nt]);
                    p.h[1] = (_Float16)(acc[nt + 4][r] + bias[nt + 4]);
                    gxbuf[sel][wb][quad * 4 + r][nt * 16 + m16] = p.u;
                }
        };

        for (int w = wave - 1; w < NWIN; w += 3) {
            const int wb = w & (NBUF - 1);
            const size_t roff = (size_t)(w * 16 + m16) * I_SZ;
            f32x4 acc[8];
            gxcompute(xbA + roff, acc);
            // back-pressure: slot wb reusable once window w-NBUF consumed
            while (__atomic_load_n(&consumed, __ATOMIC_ACQUIRE) < w - (NBUF - 1))
                __builtin_amdgcn_s_sleep(8);
            gxstore(0, wb, acc);
            gxcompute(xbB + roff, acc);
            gxstore(1, wb, acc);
            // in-order release
            while (__atomic_load_n(&produced, __ATOMIC_ACQUIRE) != w)
                __builtin_amdgcn_s_sleep(8);
            __atomic_store_n(&produced, w + 1, __ATOMIC_RELEASE);
        }
    }

    // ---------------- cooperative hist LDS -> global copy (coalesced uint4) ----------------
    __syncthreads();
    _Float16* hGA = histG + (size_t)bA * H_SZ * T_SZ;
    _Float16* hGB = histG + (size_t)bB * H_SZ * T_SZ;
    for (int i = tid; i < H_SZ * (T_SZ / 8); i += 256) {
        int r = i / (T_SZ / 8), cc = i - r * (T_SZ / 8);
        *(uint4*)(hGA + (size_t)r * T_SZ + cc * 8) = *(const uint4*)&histA[r][cc * 8];
        *(uint4*)(hGB + (size_t)r * T_SZ + cc * 8) = *(const uint4*)&histB[r][cc * 8];
    }
}

// ============ k_attn: q = Ww@h, qk = h*q, fc = <qk,Wfc> — TLP-rich ============
// Grid 128 x 13, 4 waves/block, one s-tile per wave. hist[b] staged to LDS once per
// block (51.7 KB -> 3 blocks/CU = 12 waves/CU). Verified R8/R9: ~30 us.
__global__ __launch_bounds__(256) void k_attn(
    const _Float16* __restrict__ histG, const _Float16* __restrict__ WwH,
    const float* __restrict__ bw, const float* __restrict__ Wfc,
    float* __restrict__ out)
{
    const int b    = blockIdx.x;
    const int grp  = blockIdx.y;
    const int tid  = threadIdx.x;
    const int wave = tid >> 6;
    const int lane = tid & 63;
    const int m16  = lane & 15;
    const int quad = lane >> 4;

    __shared__ __align__(16) ushort histL[H_SZ][TP];

    const _Float16* hb = histG + (size_t)b * H_SZ * T_SZ;
    for (int i = tid; i < H_SZ * (T_SZ / 8); i += 256) {
        int r = i / (T_SZ / 8), c = i - r * (T_SZ / 8);
        *(uint4*)&histL[r][c * 8] = *(const uint4*)(hb + (size_t)r * T_SZ + c * 8);
    }
    __syncthreads();

    const int st = grp * 4 + wave;
    if (st >= NTILE) return;
    const int s0 = st * 16;

    float* region = out + B_SZ + (size_t)b * T_SZ * H_SZ;
    f32x4 acc0 = (f32x4){0.f,0.f,0.f,0.f};
    f32x4 acc1 = (f32x4){0.f,0.f,0.f,0.f};
    const _Float16* wwrow = WwH + (size_t)(s0 + m16) * T_SZ;

#pragma unroll 2
    for (int t0 = 0; t0 < T_SZ; t0 += 32) {
        FragH a, b0, b1;
        a.u4  = *(const uint4*)(wwrow + t0 + quad * 8);
        b0.u4 = *(const uint4*)&histL[m16][t0 + quad * 8];
        b1.u4 = *(const uint4*)&histL[16 + m16][t0 + quad * 8];
        acc0 = __builtin_amdgcn_mfma_f32_16x16x32_f16(a.v, b0.v, acc0, 0, 0, 0);
        acc1 = __builtin_amdgcn_mfma_f32_16x16x32_f16(a.v, b1.v, acc1, 0, 0, 0);
    }

    float fc_acc = 0.f;
#pragma unroll
    for (int r = 0; r < 4; ++r) {
        int s = s0 + quad * 4 + r;
        float bws = bw[s];
        HsU u0; u0.s = histL[m16][s];      float h0 = (float)u0.h;
        HsU u1; u1.s = histL[16 + m16][s]; float h1 = (float)u1.h;
        float q0 = acc0[r] + bws;
        float q1 = acc1[r] + bws;
        float qk0 = h0 * q0;
        float qk1 = h1 * q1;
        region[(size_t)s * H_SZ + m16]      = qk0;
        region[(size_t)s * H_SZ + 16 + m16] = qk1;
        fc_acc += qk0 * Wfc[s * H_SZ + m16];
        fc_acc += qk1 * Wfc[s * H_SZ + 16 + m16];
    }

#pragma unroll
    for (int off = 32; off > 0; off >>= 1)
        fc_acc += __shfl_down(fc_acc, off, 64);
    if (lane == 0) atomicAdd(out + b, fc_acc);
}

extern "C" void kernel_launch(void* const* d_in, const int* in_sizes, int n_in,
                              void* d_out, int out_size, void* d_ws, size_t ws_size,
                              hipStream_t stream) {
    const float* x    = (const float*)d_in[0];
    const float* W_ih = (const float*)d_in[1];
    const float* W_hh = (const float*)d_in[2];
    const float* b_ih = (const float*)d_in[3];
    const float* b_hh = (const float*)d_in[4];
    const float* Ww   = (const float*)d_in[5];
    const float* bw   = (const float*)d_in[6];
    const float* Wfc  = (const float*)d_in[7];
    const float* bfc  = (const float*)d_in[8];

    float* out = (float*)d_out;

    // ws: W_ihH f16 [128][320] = 81,920 B ; WwH f16 [800][800] = 1,280,000 B ;
    //     histG f16 [128][32][800] = 6,553,600 B  (total ~7.9 MB)
    _Float16* W_ihH = (_Float16*)d_ws;
    _Float16* WwH   = (_Float16*)((char*)d_ws + (size_t)G_SZ * KPAD * 2);
    _Float16* histG = (_Float16*)((char*)d_ws + (size_t)G_SZ * KPAD * 2
                                             + (size_t)T_SZ * T_SZ * 2);

    int prep_n = G_SZ * KPAD + T_SZ * T_SZ;
    k_prep<<<(prep_n + 255) / 256, 256, 0, stream>>>(W_ih, Ww, W_ihH, WwH);
    k_main<<<B_SZ / 2, 256, 0, stream>>>(x, W_ihH, W_hh, b_ih, b_hh, bfc, histG, out);
    k_attn<<<dim3(B_SZ, NGRP), 256, 0, stream>>>(histG, WwH, bw, Wfc, out);
}

// Round 13
// 391.464 us; speedup vs baseline: 1.4695x; 1.4695x over previous
//
#include <hip/hip_runtime.h>
#include <stdint.h>

#define B_SZ 128
#define T_SZ 800
#define I_SZ 300
#define KPAD 320     // W_ih K padded with zeros to 320
#define H_SZ 32
#define G_SZ 128
#define NWIN 50      // 800 / 16
#define NBUF 4       // gx window buffers
#define TP   808     // hist stride (f16 elems): 16B-aligned rows
#define NTILE 50     // T_SZ/16 s-tiles
#define NGRP 13      // ceil(NTILE/4) tile-groups per batch

typedef float f32x4 __attribute__((ext_vector_type(4)));
typedef _Float16 half8 __attribute__((ext_vector_type(8)));
typedef _Float16 half2v __attribute__((ext_vector_type(2)));

union FragH { half8 v; _Float16 h[8]; uint4 u4; };
union PkU  { uint u; _Float16 h[2]; };
union HsU  { ushort s; _Float16 h; };
union Pk2  { uint u; half2v v; };

#if __has_builtin(__builtin_amdgcn_permlane32_swap)
#define HAVE_PL32 1
#else
#define HAVE_PL32 0
#endif

#if __has_builtin(__builtin_amdgcn_fdot2) && __has_builtin(__builtin_amdgcn_mov_dpp)
#define HAVE_DOT2 1
#else
#define HAVE_DOT2 0
#endif

__device__ __forceinline__ float tanhfast(float x) {
    float ax = fabsf(x);
    float z = __expf(-2.f * ax);
    float r = __fdividef(1.f - z, 1.f + z);
    return __builtin_copysignf(r, x);
}
__device__ __forceinline__ float sigmoidf_(float x) {
    return __fdividef(1.f, 1.f + __expf(-x));
}
__device__ __forceinline__ float bcast_lane(float v, int srclane) {
    return __int_as_float(__builtin_amdgcn_readlane(__float_as_int(v), srclane));
}

// ============ k_prep: W_ih f32 -> f16 (K zero-padded to 320); Ww f32 -> f16 ============
__global__ __launch_bounds__(256) void k_prep(
    const float* __restrict__ W_ih, const float* __restrict__ Ww,
    _Float16* __restrict__ W_ihH, _Float16* __restrict__ WwH)
{
    int i = blockIdx.x * 256 + threadIdx.x;
    if (i < G_SZ * KPAD) {
        int r = i / KPAD, k = i - r * KPAD;
        W_ihH[i] = (k < I_SZ) ? (_Float16)W_ih[r * I_SZ + k] : (_Float16)0.f;
    }
    int j = i - G_SZ * KPAD;
    if (j >= 0 && j < T_SZ * T_SZ) WwH[j] = (_Float16)Ww[j];
}

// ============ k_main: producer waves (gx MFMA) + consumer wave (scan) ============
// R11/R12 (single-variable vs R9): the per-step ds_read of gxbuf is hoisted — all 16
// window g-values are read into registers at window start (same [16][64] layout,
// conflict-free, no repacking) and the 16-step loop is FULLY unrolled so gw[tl] is
// compile-time-indexed. Per-step body has zero DS ops; tests the "DS read rides the
// dependence chain" theory (R10 falsified the fillable-stall theory).
// Scan math identical to R5/R9 (fdot2 + packed readlane + permlane32_swap).
__global__ __launch_bounds__(256) void k_main(
    const float* __restrict__ x, const _Float16* __restrict__ W_ihH,
    const float* __restrict__ W_hh,
    const float* __restrict__ b_ih, const float* __restrict__ b_hh,
    const float* __restrict__ bfc,
    _Float16* __restrict__ histG,
    float* __restrict__ out)
{
    const int b    = blockIdx.x;
    const int tid  = threadIdx.x;
    const int wave = tid >> 6;
    const int lane = tid & 63;
    const int m16  = lane & 15;
    const int quad = lane >> 4;

    __shared__ __align__(16) ushort hist[H_SZ][TP];      // 51712 B, f16 h[unit][t]
    __shared__ __align__(16) uint   gxbuf[NBUF][16][64]; // 16384 B, (gate l, gate l+64) f16 pairs
    __shared__ int produced, consumed;

    if (tid == 0) { produced = 0; consumed = 0; out[b] = bfc[0]; }  // fc init; k_attn atomic-adds
    __syncthreads();

    if (wave == 0) {
        // ---------------- consumer: LSTM scan ----------------
#if HAVE_PL32
        bool pl_pick_x;
        {
            auto t2 = __builtin_amdgcn_permlane32_swap(lane, lane, false, false);
            pl_pick_x = ((int)__builtin_amdgcn_readlane((int)t2[0], 63) < (int)H_SZ);
        }
#endif
        float c = 0.f;

#if HAVE_DOT2 && HAVE_PL32
        // W_hh rows lane / lane+64 as packed f16 pairs: WpA[j] = {W[2j], W[2j+1]}
        uint WpA[16], WpB[16];
#pragma unroll
        for (int j = 0; j < 16; ++j) {
            HsU a0_, a1_, b0_, b1_;
            a0_.h = (_Float16)W_hh[lane * H_SZ + 2*j];
            a1_.h = (_Float16)W_hh[lane * H_SZ + 2*j + 1];
            b0_.h = (_Float16)W_hh[(lane + 64) * H_SZ + 2*j];
            b1_.h = (_Float16)W_hh[(lane + 64) * H_SZ + 2*j + 1];
            WpA[j] = (uint)a0_.s | ((uint)a1_.s << 16);
            WpB[j] = (uint)b0_.s | ((uint)b1_.s << 16);
        }
        int hpk = 0;   // even lane 32+2j holds packed {h[2j], h[2j+1]} f16; h(-1)=0

        for (int w = 0; w < NWIN; ++w) {
            while (__atomic_load_n(&produced, __ATOMIC_ACQUIRE) < w + 1)
                __builtin_amdgcn_s_sleep(2);
            const int wb = w & (NBUF - 1);
            // ---- window prefetch: 16 g-words -> registers (same layout, conflict-free);
            //      per-step body below has ZERO DS ops ----
            uint gw[16];
#pragma unroll
            for (int i = 0; i < 16; ++i) gw[i] = gxbuf[wb][i][lane];
#pragma unroll
            for (int tl = 0; tl < 16; ++tl) {          // FULL unroll: gw[tl] static index
                const int t = w * 16 + tl;
                PkU g; g.u = gw[tl];
                float aA0 = 0.f, aA1 = 0.f, aB0 = 0.f, aB1 = 0.f;
#pragma unroll
                for (int j = 0; j < 16; j += 2) {
                    Pk2 h0; h0.u = (uint)__builtin_amdgcn_readlane(hpk, 32 + 2*j);
                    Pk2 h1; h1.u = (uint)__builtin_amdgcn_readlane(hpk, 32 + 2*j + 2);
                    Pk2 wa0; wa0.u = WpA[j];     Pk2 wb0; wb0.u = WpB[j];
                    Pk2 wa1; wa1.u = WpA[j + 1]; Pk2 wb1; wb1.u = WpB[j + 1];
                    aA0 = __builtin_amdgcn_fdot2(wa0.v, h0.v, aA0, false);
                    aB0 = __builtin_amdgcn_fdot2(wb0.v, h0.v, aB0, false);
                    aA1 = __builtin_amdgcn_fdot2(wa1.v, h1.v, aA1, false);
                    aB1 = __builtin_amdgcn_fdot2(wb1.v, h1.v, aB1, false);
                }
                float g0 = (aA0 + aA1) + (float)g.h[0];  // i / f
                float g1 = (aB0 + aB1) + (float)g.h[1];  // g / o

                float a0 = sigmoidf_(g0);
                float zz = (lane < H_SZ) ? g1 : 0.5f * g1;
                float th = tanhfast(zz);
                float a1 = (lane < H_SZ) ? th : 0.5f * th + 0.5f;

                float ig  = a0 * a1;                   // i*g on lanes<32
                auto rr = __builtin_amdgcn_permlane32_swap(
                    __float_as_int(ig), __float_as_int(ig), false, false);
                float igs = __int_as_float(pl_pick_x ? (int)rr[0] : (int)rr[1]);
                c = a0 * c + igs;                      // f*c + i*g   (lanes>=32 valid)
                float h = a1 * tanhfast(c);            // o*tanh(c)

                HsU hc; hc.h = (_Float16)h;
                uint hcu = (uint)hc.s;
                uint hnb = (uint)__builtin_amdgcn_mov_dpp((int)hcu, 0xB1, 0xF, 0xF, false);
                hpk = (int)((hnb << 16) | hcu);        // valid pairs on even lanes
                if (lane >= H_SZ)
                    hist[lane - H_SZ][t] = hc.s;       // f16 history -> LDS (conflict-free)
            }
            __atomic_store_n(&consumed, w + 1, __ATOMIC_RELEASE);
        }
#else
        // -------- fallback: exact R2 scalar-f32 scan --------
        float W0[H_SZ], W1[H_SZ];
#pragma unroll
        for (int k = 0; k < H_SZ; ++k) W0[k] = W_hh[lane * H_SZ + k];
#pragma unroll
        for (int k = 0; k < H_SZ; ++k) W1[k] = W_hh[(lane + 64) * H_SZ + k];
        float hprev = 0.f;

        for (int w = 0; w < NWIN; ++w) {
            while (__atomic_load_n(&produced, __ATOMIC_ACQUIRE) < w + 1)
                __builtin_amdgcn_s_sleep(2);
#pragma unroll 4
            for (int tl = 0; tl < 16; ++tl) {
                const int t = w * 16 + tl;
                PkU g; g.u = gxbuf[w & (NBUF - 1)][tl][lane];
                float p0=0.f,p1=0.f,p2=0.f,p3=0.f;
                float q0=0.f,q1=0.f,q2=0.f,q3=0.f;
#pragma unroll
                for (int k = 0; k < H_SZ; k += 4) {
                    float h0 = bcast_lane(hprev, H_SZ + k + 0);
                    float h1 = bcast_lane(hprev, H_SZ + k + 1);
                    float h2 = bcast_lane(hprev, H_SZ + k + 2);
                    float h3 = bcast_lane(hprev, H_SZ + k + 3);
                    p0 += W0[k+0]*h0; q0 += W1[k+0]*h0;
                    p1 += W0[k+1]*h1; q1 += W1[k+1]*h1;
                    p2 += W0[k+2]*h2; q2 += W1[k+2]*h2;
                    p3 += W0[k+3]*h3; q3 += W1[k+3]*h3;
                }
                float g0 = ((p0 + p1) + (p2 + p3)) + (float)g.h[0];
                float g1 = ((q0 + q1) + (q2 + q3)) + (float)g.h[1];

                float a0 = sigmoidf_(g0);
                float zz = (lane < H_SZ) ? g1 : 0.5f * g1;
                float th = tanhfast(zz);
                float a1 = (lane < H_SZ) ? th : 0.5f * th + 0.5f;

                float ig  = a0 * a1;
                float igs = __shfl_up(ig, 32, 64);
                c = a0 * c + igs;
                float h = a1 * tanhfast(c);
                hprev = h;
                if (lane >= H_SZ) {
                    HsU hs; hs.h = (_Float16)h;
                    hist[lane - H_SZ][t] = hs.s;
                }
            }
            __atomic_store_n(&consumed, w + 1, __ATOMIC_RELEASE);
        }
#endif
    } else {
        // ---------------- producers: gx windows via f16 MFMA ----------------
        float bias[8];
#pragma unroll
        for (int nt = 0; nt < 8; ++nt)
            bias[nt] = b_ih[nt * 16 + m16] + b_hh[nt * 16 + m16];
        const float* xb = x + (size_t)b * T_SZ * I_SZ;

        for (int w = wave - 1; w < NWIN; w += 3) {
            const float* xrow = xb + (size_t)(w * 16 + m16) * I_SZ;
            f32x4 acc[8];
#pragma unroll
            for (int nt = 0; nt < 8; ++nt) acc[nt] = (f32x4){0.f, 0.f, 0.f, 0.f};

            for (int ks = 0; ks < 9; ++ks) {           // k = 0..287
                const int k0 = ks * 32 + quad * 8;
                f32x4 x0 = *(const f32x4*)(xrow + k0);
                f32x4 x1 = *(const f32x4*)(xrow + k0 + 4);
                FragH a;
                a.h[0] = (_Float16)x0[0]; a.h[1] = (_Float16)x0[1];
                a.h[2] = (_Float16)x0[2]; a.h[3] = (_Float16)x0[3];
                a.h[4] = (_Float16)x1[0]; a.h[5] = (_Float16)x1[1];
                a.h[6] = (_Float16)x1[2]; a.h[7] = (_Float16)x1[3];
#pragma unroll
                for (int nt = 0; nt < 8; ++nt) {
                    FragH bb;
                    bb.u4 = *(const uint4*)(W_ihH + (size_t)(nt * 16 + m16) * KPAD + k0);
                    acc[nt] = __builtin_amdgcn_mfma_f32_16x16x32_f16(a.v, bb.v, acc[nt], 0, 0, 0);
                }
            }
            {   // tail k = 288..299 (x predicated; W_ihH zero-padded to 320)
                FragH a;
#pragma unroll
                for (int jj = 0; jj < 8; ++jj) {
                    int k = 288 + quad * 8 + jj;
                    a.h[jj] = (k < I_SZ) ? (_Float16)xrow[k] : (_Float16)0.f;
                }
#pragma unroll
                for (int nt = 0; nt < 8; ++nt) {
                    FragH bb;
                    bb.u4 = *(const uint4*)(W_ihH + (size_t)(nt * 16 + m16) * KPAD + 288 + quad * 8);
                    acc[nt] = __builtin_amdgcn_mfma_f32_16x16x32_f16(a.v, bb.v, acc[nt], 0, 0, 0);
                }
            }
            while (__atomic_load_n(&consumed, __ATOMIC_ACQUIRE) < w - (NBUF - 1))
                __builtin_amdgcn_s_sleep(8);
#pragma unroll
            for (int nt = 0; nt < 4; ++nt)
#pragma unroll
                for (int r = 0; r < 4; ++r) {
                    PkU p;
                    p.h[0] = (_Float16)(acc[nt][r]     + bias[nt]);
                    p.h[1] = (_Float16)(acc[nt + 4][r] + bias[nt + 4]);
                    gxbuf[w & (NBUF - 1)][quad * 4 + r][nt * 16 + m16] = p.u;
                }
            while (__atomic_load_n(&produced, __ATOMIC_ACQUIRE) != w)
                __builtin_amdgcn_s_sleep(8);
            __atomic_store_n(&produced, w + 1, __ATOMIC_RELEASE);
        }
    }

    // ---------------- cooperative hist LDS -> global copy (coalesced uint4) ----------------
    __syncthreads();
    _Float16* hGb = histG + (size_t)b * H_SZ * T_SZ;
    for (int i = tid; i < H_SZ * (T_SZ / 8); i += 256) {
        int r = i / (T_SZ / 8), cc = i - r * (T_SZ / 8);
        *(uint4*)(hGb + (size_t)r * T_SZ + cc * 8) = *(const uint4*)&hist[r][cc * 8];
    }
}

// ============ k_attn: q = Ww@h, qk = h*q, fc = <qk,Wfc> — TLP-rich ============
// Grid 128 x 13, 4 waves/block, one s-tile per wave. hist[b] staged to LDS once per
// block (51.7 KB -> 3 blocks/CU = 12 waves/CU). Verified R8/R9: ~30 us.
__global__ __launch_bounds__(256) void k_attn(
    const _Float16* __restrict__ histG, const _Float16* __restrict__ WwH,
    const float* __restrict__ bw, const float* __restrict__ Wfc,
    float* __restrict__ out)
{
    const int b    = blockIdx.x;
    const int grp  = blockIdx.y;
    const int tid  = threadIdx.x;
    const int wave = tid >> 6;
    const int lane = tid & 63;
    const int m16  = lane & 15;
    const int quad = lane >> 4;

    __shared__ __align__(16) ushort histL[H_SZ][TP];

    const _Float16* hb = histG + (size_t)b * H_SZ * T_SZ;
    for (int i = tid; i < H_SZ * (T_SZ / 8); i += 256) {
        int r = i / (T_SZ / 8), c = i - r * (T_SZ / 8);
        *(uint4*)&histL[r][c * 8] = *(const uint4*)(hb + (size_t)r * T_SZ + c * 8);
    }
    __syncthreads();

    const int st = grp * 4 + wave;
    if (st >= NTILE) return;
    const int s0 = st * 16;

    float* region = out + B_SZ + (size_t)b * T_SZ * H_SZ;
    f32x4 acc0 = (f32x4){0.f,0.f,0.f,0.f};
    f32x4 acc1 = (f32x4){0.f,0.f,0.f,0.f};
    const _Float16* wwrow = WwH + (size_t)(s0 + m16) * T_SZ;

#pragma unroll 2
    for (int t0 = 0; t0 < T_SZ; t0 += 32) {
        FragH a, b0, b1;
        a.u4  = *(const uint4*)(wwrow + t0 + quad * 8);
        b0.u4 = *(const uint4*)&histL[m16][t0 + quad * 8];
        b1.u4 = *(const uint4*)&histL[16 + m16][t0 + quad * 8];
        acc0 = __builtin_amdgcn_mfma_f32_16x16x32_f16(a.v, b0.v, acc0, 0, 0, 0);
        acc1 = __builtin_amdgcn_mfma_f32_16x16x32_f16(a.v, b1.v, acc1, 0, 0, 0);
    }

    float fc_acc = 0.f;
#pragma unroll
    for (int r = 0; r < 4; ++r) {
        int s = s0 + quad * 4 + r;
        float bws = bw[s];
        HsU u0; u0.s = histL[m16][s];      float h0 = (float)u0.h;
        HsU u1; u1.s = histL[16 + m16][s]; float h1 = (float)u1.h;
        float q0 = acc0[r] + bws;
        float q1 = acc1[r] + bws;
        float qk0 = h0 * q0;
        float qk1 = h1 * q1;
        region[(size_t)s * H_SZ + m16]      = qk0;
        region[(size_t)s * H_SZ + 16 + m16] = qk1;
        fc_acc += qk0 * Wfc[s * H_SZ + m16];
        fc_acc += qk1 * Wfc[s * H_SZ + 16 + m16];
    }

#pragma unroll
    for (int off = 32; off > 0; off >>= 1)
        fc_acc += __shfl_down(fc_acc, off, 64);
    if (lane == 0) atomicAdd(out + b, fc_acc);
}

extern "C" void kernel_launch(void* const* d_in, const int* in_sizes, int n_in,
                              void* d_out, int out_size, void* d_ws, size_t ws_size,
                              hipStream_t stream) {
    const float* x    = (const float*)d_in[0];
    const float* W_ih = (const float*)d_in[1];
    const float* W_hh = (const float*)d_in[2];
    const float* b_ih = (const float*)d_in[3];
    const float* b_hh = (const float*)d_in[4];
    const float* Ww   = (const float*)d_in[5];
    const float* bw   = (const float*)d_in[6];
    const float* Wfc  = (const float*)d_in[7];
    const float* bfc  = (const float*)d_in[8];

    float* out = (float*)d_out;

    // ws: W_ihH f16 [128][320] = 81,920 B ; WwH f16 [800][800] = 1,280,000 B ;
    //     histG f16 [128][32][800] = 6,553,600 B  (total ~7.9 MB)
    _Float16* W_ihH = (_Float16*)d_ws;
    _Float16* WwH   = (_Float16*)((char*)d_ws + (size_t)G_SZ * KPAD * 2);
    _Float16* histG = (_Float16*)((char*)d_ws + (size_t)G_SZ * KPAD * 2
                                             + (size_t)T_SZ * T_SZ * 2);

    int prep_n = G_SZ * KPAD + T_SZ * T_SZ;
    k_prep<<<(prep_n + 255) / 256, 256, 0, stream>>>(W_ih, Ww, W_ihH, WwH);
    k_main<<<B_SZ, 256, 0, stream>>>(x, W_ihH, W_hh, b_ih, b_hh, bfc, histG, out);
    k_attn<<<dim3(B_SZ, NGRP), 256, 0, stream>>>(histG, WwH, bw, Wfc, out);
}